// Round 17
// baseline (160.248 us; speedup 1.0000x reference)
//
#include <hip/hip_runtime.h>
#include <math.h>

// Problem constants
#define NB 32
#define CI 64
#define CO 64
#define CA 16
#define NK 4
#define HH 128
#define WW 128
#define EPSBN 1e-5f

typedef __bf16 bf16x8 __attribute__((ext_vector_type(8)));
typedef float f32x4 __attribute__((ext_vector_type(4)));

__device__ inline unsigned short f2bf(float f) {
    union { float f; unsigned u; } c; c.f = f;
    return (unsigned short)((c.u + 0x7fffu + ((c.u >> 16) & 1u)) >> 16);
}

// packed 2xf32 -> 2xbf16 (lo = first arg), single VALU op
__device__ inline unsigned cvt_pk_bf16(float lo, float hi) {
    unsigned r;
    asm("v_cvt_pk_bf16_f32 %0, %1, %2" : "=v"(r) : "v"(lo), "v"(hi));
    return r;
}

__device__ inline void gload_lds16(const void* g, void* l) {
    __builtin_amdgcn_global_load_lds(
        (const __attribute__((address_space(1))) unsigned int*)g,
        (__attribute__((address_space(3))) unsigned int*)l, 16, 0, 0);
}

// Workspace layout (float offsets). ~2.4 MB total.
#define WS_ZERO   0             // 64 (zero page for OOB pointer-select)
#define WS_POOLED 64            // 2048
#define WS_W2T    8192          // 1179648 ushorts

// ===========================================================================
// 1) pool: pure streaming reduce. Block = (b,ci) plane (64KB contiguous).
//    Also zeroes the 64-float zero page (block 0) for conv's OOB selects.
// ===========================================================================
__global__ __launch_bounds__(256, 4) void pool_kernel(const float* __restrict__ x,
                                                      float* __restrict__ pooled,
                                                      float* __restrict__ zeros) {
    if (blockIdx.x == 0 && threadIdx.x < 64) zeros[threadIdx.x] = 0.f;
    const int plane = blockIdx.x;               // 2048
    const float4* p = (const float4*)(x + (size_t)plane * (HH * WW));
    float4 v[16];
    #pragma unroll
    for (int i = 0; i < 16; ++i) v[i] = p[threadIdx.x + 256 * i];
    float s = 0.f;
    #pragma unroll
    for (int i = 0; i < 16; ++i) s += v[i].x + v[i].y + v[i].z + v[i].w;
    #pragma unroll
    for (int off = 32; off > 0; off >>= 1) s += __shfl_down(s, off);
    __shared__ float red[4];
    if ((threadIdx.x & 63) == 0) red[threadIdx.x >> 6] = s;
    __syncthreads();
    if (threadIdx.x == 0)
        pooled[plane] = red[0] + red[1] + red[2] + red[3];   // sum; scaled below
}

// ===========================================================================
// 2) w2t3: attention (recomputed per block, tiny) + folded weights
//    w2t[b][tap][o][i] bf16. Block = (b, o-quad), 256 thr; lanes = i
//    (128B-line writes). Per-thread attention cost ~300 FMA, L2-hot reads.
// ===========================================================================
__global__ __launch_bounds__(256) void w2t3(
    const float* __restrict__ kernels, const float* __restrict__ pooled,
    const float* __restrict__ prep_w,
    const float* __restrict__ bn_g, const float* __restrict__ bn_b,
    const float* __restrict__ bn_m, const float* __restrict__ bn_v,
    const float* __restrict__ fc_sp_w, const float* __restrict__ fc_sp_b,
    const float* __restrict__ fc_ch_w, const float* __restrict__ fc_ch_b,
    const float* __restrict__ fc_f_w,  const float* __restrict__ fc_f_b,
    const float* __restrict__ fc_k_w,  const float* __restrict__ fc_k_b,
    unsigned short* __restrict__ w2t) {
    const int bid = blockIdx.x;              // 32*16
    const int b  = bid >> 4;
    const int wv = threadIdx.x >> 6;
    const int o  = (bid & 15) * 4 + wv;
    const int lane = threadIdx.x & 63;
    const int i  = lane;
    const float scale = 1.f / (HH * WW);

    // kernels reads first (deepest latency)
    float kw[NK][9];
    #pragma unroll
    for (int k = 0; k < NK; ++k) {
        const float* kp = kernels + ((size_t)(k * CO + o) * CI + i) * 9;
        #pragma unroll
        for (int t = 0; t < 9; ++t) kw[k][t] = kp[t];
    }

    // attention trunk: lane computes att[a] for a = lane&15, then shfl-gather
    const int a_ = lane & 15;
    float att;
    {
        float s = 0.f;
        const float* pv = pooled + b * CI;
        const float* wv_ = prep_w + a_ * CI;
        #pragma unroll
        for (int c = 0; c < CI; ++c) s += pv[c] * wv_[c];
        s = (s * scale - bn_m[a_]) * rsqrtf(bn_v[a_] + EPSBN) * bn_g[a_] + bn_b[a_];
        att = fmaxf(s, 0.f);
    }
    float av[CA];
    #pragma unroll
    for (int k = 0; k < CA; ++k) av[k] = __shfl(att, (lane & 48) + k);

    // heads: cha_i, fa_o, ka[4] softmax, sp[9]
    float cha_i, fa_o;
    {
        float s1 = fc_ch_b[i], s2 = fc_f_b[o];
        #pragma unroll
        for (int k = 0; k < CA; ++k) {
            s1 += av[k] * fc_ch_w[i * CA + k];
            s2 += av[k] * fc_f_w[o * CA + k];
        }
        cha_i = 1.f / (1.f + expf(-s1));
        fa_o  = 1.f / (1.f + expf(-s2));
    }
    float kav[NK];
    {
        float kv[NK], m = -1e30f;
        #pragma unroll
        for (int k = 0; k < NK; ++k) {
            float s = fc_k_b[k];
            #pragma unroll
            for (int t = 0; t < CA; ++t) s += av[t] * fc_k_w[k * CA + t];
            kv[k] = s; m = fmaxf(m, s);
        }
        float den = 0.f;
        #pragma unroll
        for (int k = 0; k < NK; ++k) { kv[k] = expf(kv[k] - m); den += kv[k]; }
        #pragma unroll
        for (int k = 0; k < NK; ++k) kav[k] = kv[k] / den;
    }
    float spv[9];
    #pragma unroll
    for (int t = 0; t < 9; ++t) {
        float s = fc_sp_b[t];
        #pragma unroll
        for (int k = 0; k < CA; ++k) s += av[k] * fc_sp_w[t * CA + k];
        spv[t] = 1.f / (1.f + expf(-s));
    }

    const float base = cha_i * fa_o;
    #pragma unroll
    for (int tap = 0; tap < 9; ++tap) {
        float s = 0.f;
        #pragma unroll
        for (int k = 0; k < NK; ++k) s += kav[k] * kw[k][tap];
        w2t[((size_t)(b * 9 + tap) * CO + o) * CI + i] = f2bf(s * spv[tap] * base);
    }
}

// ===========================================================================
// 3) FUSED conv (mfma_f32_16x16x32_bf16), dense-lane batched x staging +
//    T14 async-split A staging: phase c issues reg-loads of A(c+2), runs
//    MFMA, then ds_writes A(c+1) -> barrier drains nothing global.
//    Block = 64co x 32col x 4row, 256 thr / 4 waves (cohalf x colh).
//    LDS 51200B = x 26624 (oct-XOR) + A dbuf 2 x 12288. 3 blocks/CU.
// ===========================================================================
#define ABASE 26624
#define ABUFB 12288

__global__ __launch_bounds__(256, 3) void conv_fused(const float* __restrict__ x,
                                                     const unsigned short* __restrict__ w2t,
                                                     const float* __restrict__ zeros,
                                                     float* __restrict__ out) {
    __shared__ __align__(16) unsigned char xs[ABASE + 2 * ABUFB];   // 51200
    const int tid  = threadIdx.x;
    const int lane = tid & 63;
    const int wv   = tid >> 6;
    const int orig = blockIdx.x;
    const int bid  = (orig & 7) * 512 + (orig >> 3);    // XCD swizzle (4096 = 8*512)
    const int b    = bid >> 7;
    const int rem  = bid & 127;
    const int colg = rem & 3;
    const int hg   = rem >> 2;
    const int h0 = hg * 4;
    const int w0 = colg * 32;

    const unsigned short* w2base = w2t + (size_t)b * 36864;

    // A staging, T14-split. Thread t stages units (u=j, q=t>>6, o=t&63).
    const int aq = tid >> 6, ao = tid & 63;
    uint4 Areg[2][3];
    auto AloadReg = [&](int c) {         // c compile-time after unroll
        const int ks = c / 3, v = c - ks * 3;
        #pragma unroll
        for (int j = 0; j < 3; ++j)
            Areg[c & 1][j] = *(const uint4*)(w2base + (size_t)(j * 3 + v) * 4096
                                             + ao * 64 + ks * 32 + aq * 8);
    };
    auto AwriteLds = [&](int c) {
        unsigned char* abuf = xs + ABASE + (c & 1) * ABUFB;
        #pragma unroll
        for (int j = 0; j < 3; ++j)
            *(uint4*)(abuf + j * 4096 + aq * 1024 + ao * 16) = Areg[c & 1][j];
    };
    // chunk 0 via gload_lds (covered by the x-stage barrier)
    {
        for (int ch = wv; ch < 12; ch += 4) {
            const int u = ch >> 2, q = ch & 3;
            gload_lds16(w2base + (size_t)(u * 3 + 0) * 4096 + lane * 64 + q * 8,
                        xs + ABASE + (ch << 10));
        }
    }

    // ---- x-stage, dense-lane mapping, batched loads (zeros-page select)
    const int qlane = lane & 3;
    const int g     = lane >> 2;
    float4 La[9], Lb[9];
    #pragma unroll
    for (int it = 0; it < 9; ++it) {
        const int base = (wv * 9 + it) * 16;
        const int blk  = base >> 5;              // row*3 + iq
        const int row  = blk / 3;
        const int iq   = blk - row * 3;
        const int cip  = (base & 31) + g;
        const int hh   = h0 - 1 + row;
        const int cg   = w0 - 8 + iq * 16 + qlane * 4;
        const bool ok  = ((unsigned)hh < (unsigned)HH) && ((unsigned)cg <= 124u);
        const float* p0 = x + ((size_t)(b * CI + 2 * cip) * HH + hh) * WW + cg;
        const float* pa = ok ? p0 : zeros;
        const float* pb = ok ? (p0 + HH * WW) : zeros;
        La[it] = *(const float4*)pa;
        Lb[it] = *(const float4*)pb;
    }
    // A chunk 1 reg-loads in flight under the x convert/write
    AloadReg(1);

    #pragma unroll
    for (int it = 0; it < 9; ++it) {
        const int base = (wv * 9 + it) * 16;
        const int blk  = base >> 5;
        const int row  = blk / 3;
        const int iq   = blk - row * 3;
        const int cip  = (base & 31) + g;
        unsigned char* rbase = xs + row * 4352;
        const int oct = cip >> 2, lo = (cip & 3) * 4;
        const float av[4] = {La[it].x, La[it].y, La[it].z, La[it].w};
        const float cv[4] = {Lb[it].x, Lb[it].y, Lb[it].z, Lb[it].w};
        #pragma unroll
        for (int e = 0; e < 4; ++e) {
            const int cl_ = iq * 16 + qlane * 4 + e - 7;
            if ((unsigned)cl_ < 34u) {
                *(unsigned*)(rbase + cl_ * 128 + ((oct ^ (cl_ & 7)) << 4) + lo) =
                    cvt_pk_bf16(av[e], cv[e]);
            }
        }
    }
    __syncthreads();

    const int cl = lane & 15;        // pixel col in 16 / o in 16
    const int kq = lane >> 4;        // k-quarter within ks-half (8 ci)
    const int cohalf = wv & 1;
    const int colh   = wv >> 1;      // 0..1

    f32x4 acc[2][4];
    #pragma unroll
    for (int og = 0; og < 2; ++og)
        #pragma unroll
        for (int t = 0; t < 4; ++t)
            #pragma unroll
            for (int e = 0; e < 4; ++e) acc[og][t][e] = 0.f;

    const int lcol0 = colh * 16 + cl;
    const int aoff  = kq * 1024 + (cohalf * 32 + cl) * 16;

    // ---- 6 phases: load A(c+2) -> compute c -> write A(c+1) -> barrier
    #pragma unroll
    for (int c = 0; c < 6; ++c) {
        const int ks = c / 3, v = c - ks * 3;
        if (c < 4) AloadReg(c + 2);
        const unsigned char* abuf = xs + ABASE + (c & 1) * ABUFB;
        const int lcol = lcol0 + v;
        const int sw = ((ks << 2) + kq) ^ (lcol & 7);
        const unsigned char* bp = xs + (((lcol << 3) + sw) << 4);
        bf16x8 Bf[6];
        #pragma unroll
        for (int r = 0; r < 6; ++r) Bf[r] = *(const bf16x8*)(bp + r * 4352);
        __builtin_amdgcn_s_setprio(1);
        #pragma unroll
        for (int u = 0; u < 3; ++u) {
            const unsigned char* ap = abuf + u * 4096 + aoff;
            const bf16x8 A0 = *(const bf16x8*)(ap);
            const bf16x8 A1 = *(const bf16x8*)(ap + 256);     // og=1: +16 o
            #pragma unroll
            for (int t = 0; t < 4; ++t)
                acc[0][t] = __builtin_amdgcn_mfma_f32_16x16x32_bf16(A0, Bf[t + u], acc[0][t], 0, 0, 0);
            #pragma unroll
            for (int t = 0; t < 4; ++t)
                acc[1][t] = __builtin_amdgcn_mfma_f32_16x16x32_bf16(A1, Bf[t + u], acc[1][t], 0, 0, 0);
        }
        __builtin_amdgcn_s_setprio(0);
        if (c < 5) {
            AwriteLds(c + 1);
            __syncthreads();
        }
    }

    // ---- epilogue: o = cohalf*32 + og*16 + kq*4 + rg, col = w0 + colh*16 + cl
    #pragma unroll
    for (int og = 0; og < 2; ++og)
        #pragma unroll
        for (int t = 0; t < 4; ++t) {
            float* op = out + ((size_t)(b * CO + cohalf * 32 + og * 16 + kq * 4) * HH + h0 + t) * WW
                      + w0 + colh * 16 + cl;
            #pragma unroll
            for (int rg = 0; rg < 4; ++rg)
                op[(size_t)rg * (HH * WW)] = acc[og][t][rg];
        }
}

// ===========================================================================
extern "C" void kernel_launch(void* const* d_in, const int* in_sizes, int n_in,
                              void* d_out, int out_size, void* d_ws, size_t ws_size,
                              hipStream_t stream) {
    const float* x        = (const float*)d_in[0];
    const float* prep_w   = (const float*)d_in[1];
    const float* bn_g     = (const float*)d_in[2];
    const float* bn_b     = (const float*)d_in[3];
    const float* bn_m     = (const float*)d_in[4];
    const float* bn_v     = (const float*)d_in[5];
    const float* fc_sp_w  = (const float*)d_in[6];
    const float* fc_sp_b  = (const float*)d_in[7];
    const float* fc_ch_w  = (const float*)d_in[8];
    const float* fc_ch_b  = (const float*)d_in[9];
    const float* fc_f_w   = (const float*)d_in[10];
    const float* fc_f_b   = (const float*)d_in[11];
    const float* fc_k_w   = (const float*)d_in[12];
    const float* fc_k_b   = (const float*)d_in[13];
    const float* kernels  = (const float*)d_in[14];
    float* out = (float*)d_out;
    float* ws  = (float*)d_ws;

    float* zeros  = ws + WS_ZERO;
    float* pooled = ws + WS_POOLED;
    unsigned short* w2t = (unsigned short*)(ws + WS_W2T);

    pool_kernel<<<NB * CI, 256, 0, stream>>>(x, pooled, zeros);
    w2t3<<<NB * 16, 256, 0, stream>>>(kernels, pooled, prep_w,
                                      bn_g, bn_b, bn_m, bn_v,
                                      fc_sp_w, fc_sp_b, fc_ch_w, fc_ch_b,
                                      fc_f_w, fc_f_b, fc_k_w, fc_k_b, w2t);
    conv_fused<<<4096, 256, 0, stream>>>(x, w2t, zeros, out);
}

// Round 18
// 112.417 us; speedup vs baseline: 1.4255x; 1.4255x over previous
//
#include <hip/hip_runtime.h>
#include <math.h>

// Problem constants
#define NB 32
#define CI 64
#define CO 64
#define CA 16
#define NK 4
#define HH 128
#define WW 128
#define EPSBN 1e-5f

typedef __bf16 bf16x8 __attribute__((ext_vector_type(8)));
typedef float f32x4 __attribute__((ext_vector_type(4)));

__device__ inline unsigned short f2bf(float f) {
    union { float f; unsigned u; } c; c.f = f;
    return (unsigned short)((c.u + 0x7fffu + ((c.u >> 16) & 1u)) >> 16);
}

// packed 2xf32 -> 2xbf16 (lo = first arg), single VALU op
__device__ inline unsigned cvt_pk_bf16(float lo, float hi) {
    unsigned r;
    asm("v_cvt_pk_bf16_f32 %0, %1, %2" : "=v"(r) : "v"(lo), "v"(hi));
    return r;
}

__device__ inline void gload_lds16(const void* g, void* l) {
    __builtin_amdgcn_global_load_lds(
        (const __attribute__((address_space(1))) unsigned int*)g,
        (__attribute__((address_space(3))) unsigned int*)l, 16, 0, 0);
}

// Workspace layout (float offsets). ~2.4 MB total.
#define WS_ZERO   0             // 64 (zero page for OOB pointer-select)
#define WS_POOLED 64            // 2048
#define WS_W2T    8192          // 1179648 ushorts

// ===========================================================================
// 1) pool: pure streaming reduce. Block = (b,ci) plane (64KB contiguous).
//    Also zeroes the 64-float zero page (block 0) for conv's OOB selects.
// ===========================================================================
__global__ __launch_bounds__(256, 4) void pool_kernel(const float* __restrict__ x,
                                                      float* __restrict__ pooled,
                                                      float* __restrict__ zeros) {
    if (blockIdx.x == 0 && threadIdx.x < 64) zeros[threadIdx.x] = 0.f;
    const int plane = blockIdx.x;               // 2048
    const float4* p = (const float4*)(x + (size_t)plane * (HH * WW));
    float4 v[16];
    #pragma unroll
    for (int i = 0; i < 16; ++i) v[i] = p[threadIdx.x + 256 * i];
    float s = 0.f;
    #pragma unroll
    for (int i = 0; i < 16; ++i) s += v[i].x + v[i].y + v[i].z + v[i].w;
    #pragma unroll
    for (int off = 32; off > 0; off >>= 1) s += __shfl_down(s, off);
    __shared__ float red[4];
    if ((threadIdx.x & 63) == 0) red[threadIdx.x >> 6] = s;
    __syncthreads();
    if (threadIdx.x == 0)
        pooled[plane] = red[0] + red[1] + red[2] + red[3];   // sum; scaled below
}

// ===========================================================================
// 2) w2t3: attention (recomputed per block, tiny) + folded weights
//    w2t[b][tap][o][i] bf16. Block = (b, o-quad), 256 thr; lanes = i
//    (128B-line writes). r17-proven correct.
// ===========================================================================
__global__ __launch_bounds__(256) void w2t3(
    const float* __restrict__ kernels, const float* __restrict__ pooled,
    const float* __restrict__ prep_w,
    const float* __restrict__ bn_g, const float* __restrict__ bn_b,
    const float* __restrict__ bn_m, const float* __restrict__ bn_v,
    const float* __restrict__ fc_sp_w, const float* __restrict__ fc_sp_b,
    const float* __restrict__ fc_ch_w, const float* __restrict__ fc_ch_b,
    const float* __restrict__ fc_f_w,  const float* __restrict__ fc_f_b,
    const float* __restrict__ fc_k_w,  const float* __restrict__ fc_k_b,
    unsigned short* __restrict__ w2t) {
    const int bid = blockIdx.x;              // 32*16
    const int b  = bid >> 4;
    const int wv = threadIdx.x >> 6;
    const int o  = (bid & 15) * 4 + wv;
    const int lane = threadIdx.x & 63;
    const int i  = lane;
    const float scale = 1.f / (HH * WW);

    float kw[NK][9];
    #pragma unroll
    for (int k = 0; k < NK; ++k) {
        const float* kp = kernels + ((size_t)(k * CO + o) * CI + i) * 9;
        #pragma unroll
        for (int t = 0; t < 9; ++t) kw[k][t] = kp[t];
    }

    const int a_ = lane & 15;
    float att;
    {
        float s = 0.f;
        const float* pv = pooled + b * CI;
        const float* wv_ = prep_w + a_ * CI;
        #pragma unroll
        for (int c = 0; c < CI; ++c) s += pv[c] * wv_[c];
        s = (s * scale - bn_m[a_]) * rsqrtf(bn_v[a_] + EPSBN) * bn_g[a_] + bn_b[a_];
        att = fmaxf(s, 0.f);
    }
    float av[CA];
    #pragma unroll
    for (int k = 0; k < CA; ++k) av[k] = __shfl(att, (lane & 48) + k);

    float cha_i, fa_o;
    {
        float s1 = fc_ch_b[i], s2 = fc_f_b[o];
        #pragma unroll
        for (int k = 0; k < CA; ++k) {
            s1 += av[k] * fc_ch_w[i * CA + k];
            s2 += av[k] * fc_f_w[o * CA + k];
        }
        cha_i = 1.f / (1.f + expf(-s1));
        fa_o  = 1.f / (1.f + expf(-s2));
    }
    float kav[NK];
    {
        float kv[NK], m = -1e30f;
        #pragma unroll
        for (int k = 0; k < NK; ++k) {
            float s = fc_k_b[k];
            #pragma unroll
            for (int t = 0; t < CA; ++t) s += av[t] * fc_k_w[k * CA + t];
            kv[k] = s; m = fmaxf(m, s);
        }
        float den = 0.f;
        #pragma unroll
        for (int k = 0; k < NK; ++k) { kv[k] = expf(kv[k] - m); den += kv[k]; }
        #pragma unroll
        for (int k = 0; k < NK; ++k) kav[k] = kv[k] / den;
    }
    float spv[9];
    #pragma unroll
    for (int t = 0; t < 9; ++t) {
        float s = fc_sp_b[t];
        #pragma unroll
        for (int k = 0; k < CA; ++k) s += av[k] * fc_sp_w[t * CA + k];
        spv[t] = 1.f / (1.f + expf(-s));
    }

    const float base = cha_i * fa_o;
    #pragma unroll
    for (int tap = 0; tap < 9; ++tap) {
        float s = 0.f;
        #pragma unroll
        for (int k = 0; k < NK; ++k) s += kav[k] * kw[k][tap];
        w2t[((size_t)(b * 9 + tap) * CO + o) * CI + i] = f2bf(s * spv[tap] * base);
    }
}

// ===========================================================================
// 3) FUSED conv (mfma_f32_16x16x32_bf16): r16 structure (gload_lds A staging,
//    dense-lane batched x staging) + TRIPLE-buffered A with counted vmcnt:
//    phase c stages A(c+2); end-of-phase waits vmcnt(3) (A(c+1) landed,
//    A(c+2) stays in flight) + raw s_barrier — the barrier never drains
//    fresh loads (T4, m218 pattern). A(0), A(1) staged in prologue (covered
//    by the x-stage __syncthreads).
//    Block = 64co x 32col x 4row, 256 thr / 4 waves (cohalf x colh).
//    LDS 63488B = x 26624 (oct-XOR) + A 3 x 12288. 2 blocks/CU.
// ===========================================================================
#define ABASE 26624
#define ABUFB 12288

__global__ __launch_bounds__(256, 2) void conv_fused(const float* __restrict__ x,
                                                     const unsigned short* __restrict__ w2t,
                                                     const float* __restrict__ zeros,
                                                     float* __restrict__ out) {
    __shared__ __align__(16) unsigned char xs[ABASE + 3 * ABUFB];   // 63488
    const int tid  = threadIdx.x;
    const int lane = tid & 63;
    const int wv   = tid >> 6;
    const int orig = blockIdx.x;
    const int bid  = (orig & 7) * 512 + (orig >> 3);    // XCD swizzle (4096 = 8*512)
    const int b    = bid >> 7;
    const int rem  = bid & 127;
    const int colg = rem & 3;
    const int hg   = rem >> 2;
    const int h0 = hg * 4;
    const int w0 = colg * 32;

    const unsigned short* w2base = w2t + (size_t)b * 36864;

    // A chunk stager: chunk c = (ks = c/3, v = c%3) -> buf (c%3).
    // 12 units: u = ch>>2, q = ch&3; lanes = o. 3 gload_lds per wave.
    auto stageA = [&](int c) {
        const int ks = c / 3, v = c - ks * 3;
        unsigned char* abuf = xs + ABASE + (c % 3) * ABUFB;
        for (int ch = wv; ch < 12; ch += 4) {
            const int u  = ch >> 2;
            const int q  = ch & 3;
            const unsigned short* g = w2base + (size_t)(u * 3 + v) * 4096
                                    + lane * 64 + ks * 32 + q * 8;
            gload_lds16(g, abuf + (ch << 10));
        }
    };

    // ---- prologue: A(0) gloads, then batched x loads, then A(1) gloads
    stageA(0);

    const int qlane = lane & 3;
    const int g     = lane >> 2;
    float4 La[9], Lb[9];
    #pragma unroll
    for (int it = 0; it < 9; ++it) {
        const int base = (wv * 9 + it) * 16;
        const int blk  = base >> 5;              // row*3 + iq
        const int row  = blk / 3;
        const int iq   = blk - row * 3;
        const int cip  = (base & 31) + g;
        const int hh   = h0 - 1 + row;
        const int cg   = w0 - 8 + iq * 16 + qlane * 4;
        const bool ok  = ((unsigned)hh < (unsigned)HH) && ((unsigned)cg <= 124u);
        const float* p0 = x + ((size_t)(b * CI + 2 * cip) * HH + hh) * WW + cg;
        const float* pa = ok ? p0 : zeros;
        const float* pb = ok ? (p0 + HH * WW) : zeros;
        La[it] = *(const float4*)pa;
        Lb[it] = *(const float4*)pb;
    }
    stageA(1);

    #pragma unroll
    for (int it = 0; it < 9; ++it) {
        const int base = (wv * 9 + it) * 16;
        const int blk  = base >> 5;
        const int row  = blk / 3;
        const int iq   = blk - row * 3;
        const int cip  = (base & 31) + g;
        unsigned char* rbase = xs + row * 4352;
        const int oct = cip >> 2, lo = (cip & 3) * 4;
        const float av[4] = {La[it].x, La[it].y, La[it].z, La[it].w};
        const float cv[4] = {Lb[it].x, Lb[it].y, Lb[it].z, Lb[it].w};
        #pragma unroll
        for (int e = 0; e < 4; ++e) {
            const int cl_ = iq * 16 + qlane * 4 + e - 7;
            if ((unsigned)cl_ < 34u) {
                *(unsigned*)(rbase + cl_ * 128 + ((oct ^ (cl_ & 7)) << 4) + lo) =
                    cvt_pk_bf16(av[e], cv[e]);
            }
        }
    }
    __syncthreads();   // drains everything: x, A(0), A(1)

    const int cl = lane & 15;        // pixel col in 16 / o in 16
    const int kq = lane >> 4;        // k-quarter within ks-half (8 ci)
    const int cohalf = wv & 1;
    const int colh   = wv >> 1;      // 0..1

    f32x4 acc[2][4];
    #pragma unroll
    for (int og = 0; og < 2; ++og)
        #pragma unroll
        for (int t = 0; t < 4; ++t)
            #pragma unroll
            for (int e = 0; e < 4; ++e) acc[og][t][e] = 0.f;

    const int lcol0 = colh * 16 + cl;
    const int aoff  = kq * 1024 + (cohalf * 32 + cl) * 16;

    // ---- 6 phases: stage A(c+2) -> compute c -> vmcnt(3) + s_barrier
    #pragma unroll
    for (int c = 0; c < 6; ++c) {
        const int ks = c / 3, v = c - ks * 3;
        if (c < 4) stageA(c + 2);
        const unsigned char* abuf = xs + ABASE + (c % 3) * ABUFB;
        const int lcol = lcol0 + v;
        const int sw = ((ks << 2) + kq) ^ (lcol & 7);
        const unsigned char* bp = xs + (((lcol << 3) + sw) << 4);
        bf16x8 Bf[6];
        #pragma unroll
        for (int r = 0; r < 6; ++r) Bf[r] = *(const bf16x8*)(bp + r * 4352);
        __builtin_amdgcn_s_setprio(1);
        #pragma unroll
        for (int u = 0; u < 3; ++u) {
            const unsigned char* ap = abuf + u * 4096 + aoff;
            const bf16x8 A0 = *(const bf16x8*)(ap);
            const bf16x8 A1 = *(const bf16x8*)(ap + 256);     // og=1: +16 o
            #pragma unroll
            for (int t = 0; t < 4; ++t)
                acc[0][t] = __builtin_amdgcn_mfma_f32_16x16x32_bf16(A0, Bf[t + u], acc[0][t], 0, 0, 0);
            #pragma unroll
            for (int t = 0; t < 4; ++t)
                acc[1][t] = __builtin_amdgcn_mfma_f32_16x16x32_bf16(A1, Bf[t + u], acc[1][t], 0, 0, 0);
        }
        __builtin_amdgcn_s_setprio(0);
        if (c < 4) {
            asm volatile("s_waitcnt vmcnt(3)" ::: "memory");   // A(c+1) landed; A(c+2) in flight
            __builtin_amdgcn_s_barrier();
            __builtin_amdgcn_sched_barrier(0);
        } else if (c == 4) {
            asm volatile("s_waitcnt vmcnt(0)" ::: "memory");   // A(5) landed
            __builtin_amdgcn_s_barrier();
            __builtin_amdgcn_sched_barrier(0);
        }
    }

    // ---- epilogue: o = cohalf*32 + og*16 + kq*4 + rg, col = w0 + colh*16 + cl
    #pragma unroll
    for (int og = 0; og < 2; ++og)
        #pragma unroll
        for (int t = 0; t < 4; ++t) {
            float* op = out + ((size_t)(b * CO + cohalf * 32 + og * 16 + kq * 4) * HH + h0 + t) * WW
                      + w0 + colh * 16 + cl;
            #pragma unroll
            for (int rg = 0; rg < 4; ++rg)
                op[(size_t)rg * (HH * WW)] = acc[og][t][rg];
        }
}

// ===========================================================================
extern "C" void kernel_launch(void* const* d_in, const int* in_sizes, int n_in,
                              void* d_out, int out_size, void* d_ws, size_t ws_size,
                              hipStream_t stream) {
    const float* x        = (const float*)d_in[0];
    const float* prep_w   = (const float*)d_in[1];
    const float* bn_g     = (const float*)d_in[2];
    const float* bn_b     = (const float*)d_in[3];
    const float* bn_m     = (const float*)d_in[4];
    const float* bn_v     = (const float*)d_in[5];
    const float* fc_sp_w  = (const float*)d_in[6];
    const float* fc_sp_b  = (const float*)d_in[7];
    const float* fc_ch_w  = (const float*)d_in[8];
    const float* fc_ch_b  = (const float*)d_in[9];
    const float* fc_f_w   = (const float*)d_in[10];
    const float* fc_f_b   = (const float*)d_in[11];
    const float* fc_k_w   = (const float*)d_in[12];
    const float* fc_k_b   = (const float*)d_in[13];
    const float* kernels  = (const float*)d_in[14];
    float* out = (float*)d_out;
    float* ws  = (float*)d_ws;

    float* zeros  = ws + WS_ZERO;
    float* pooled = ws + WS_POOLED;
    unsigned short* w2t = (unsigned short*)(ws + WS_W2T);

    pool_kernel<<<NB * CI, 256, 0, stream>>>(x, pooled, zeros);
    w2t3<<<NB * 16, 256, 0, stream>>>(kernels, pooled, prep_w,
                                      bn_g, bn_b, bn_m, bn_v,
                                      fc_sp_w, fc_sp_b, fc_ch_w, fc_ch_b,
                                      fc_f_w, fc_f_b, fc_k_w, fc_k_b, w2t);
    conv_fused<<<4096, 256, 0, stream>>>(x, w2t, zeros, out);
}

// Round 19
// 106.588 us; speedup vs baseline: 1.5034x; 1.0547x over previous
//
#include <hip/hip_runtime.h>
#include <math.h>

// Problem constants
#define NB 32
#define CI 64
#define CO 64
#define CA 16
#define NK 4
#define HH 128
#define WW 128
#define EPSBN 1e-5f

typedef __bf16 bf16x8 __attribute__((ext_vector_type(8)));
typedef float f32x4 __attribute__((ext_vector_type(4)));

__device__ inline unsigned short f2bf(float f) {
    union { float f; unsigned u; } c; c.f = f;
    return (unsigned short)((c.u + 0x7fffu + ((c.u >> 16) & 1u)) >> 16);
}

// packed 2xf32 -> 2xbf16 (lo = first arg), single VALU op
__device__ inline unsigned cvt_pk_bf16(float lo, float hi) {
    unsigned r;
    asm("v_cvt_pk_bf16_f32 %0, %1, %2" : "=v"(r) : "v"(lo), "v"(hi));
    return r;
}

__device__ inline void gload_lds16(const void* g, void* l) {
    __builtin_amdgcn_global_load_lds(
        (const __attribute__((address_space(1))) unsigned int*)g,
        (__attribute__((address_space(3))) unsigned int*)l, 16, 0, 0);
}

// Workspace layout (float offsets). ~2.4 MB total.
#define WS_ZERO   0             // 64 (zero page for OOB pointer-select)
#define WS_POOLED 64            // 2048
#define WS_W2T    8192          // 1179648 ushorts

// ===========================================================================
// 1) pool: pure streaming reduce. Block = (b,ci) plane (64KB contiguous).
//    Also zeroes the 64-float zero page (block 0) for conv's OOB selects.
// ===========================================================================
__global__ __launch_bounds__(256, 4) void pool_kernel(const float* __restrict__ x,
                                                      float* __restrict__ pooled,
                                                      float* __restrict__ zeros) {
    if (blockIdx.x == 0 && threadIdx.x < 64) zeros[threadIdx.x] = 0.f;
    const int plane = blockIdx.x;               // 2048
    const float4* p = (const float4*)(x + (size_t)plane * (HH * WW));
    float4 v[16];
    #pragma unroll
    for (int i = 0; i < 16; ++i) v[i] = p[threadIdx.x + 256 * i];
    float s = 0.f;
    #pragma unroll
    for (int i = 0; i < 16; ++i) s += v[i].x + v[i].y + v[i].z + v[i].w;
    #pragma unroll
    for (int off = 32; off > 0; off >>= 1) s += __shfl_down(s, off);
    __shared__ float red[4];
    if ((threadIdx.x & 63) == 0) red[threadIdx.x >> 6] = s;
    __syncthreads();
    if (threadIdx.x == 0)
        pooled[plane] = red[0] + red[1] + red[2] + red[3];   // sum; scaled below
}

// ===========================================================================
// 2) w2t3: attention (recomputed per block, tiny) + folded weights
//    w2t[b][tap][o][i] bf16. Block = (b, o-quad), 256 thr; lanes = i
//    (128B-line writes). r17/r18-proven.
// ===========================================================================
__global__ __launch_bounds__(256) void w2t3(
    const float* __restrict__ kernels, const float* __restrict__ pooled,
    const float* __restrict__ prep_w,
    const float* __restrict__ bn_g, const float* __restrict__ bn_b,
    const float* __restrict__ bn_m, const float* __restrict__ bn_v,
    const float* __restrict__ fc_sp_w, const float* __restrict__ fc_sp_b,
    const float* __restrict__ fc_ch_w, const float* __restrict__ fc_ch_b,
    const float* __restrict__ fc_f_w,  const float* __restrict__ fc_f_b,
    const float* __restrict__ fc_k_w,  const float* __restrict__ fc_k_b,
    unsigned short* __restrict__ w2t) {
    const int bid = blockIdx.x;              // 32*16
    const int b  = bid >> 4;
    const int wv = threadIdx.x >> 6;
    const int o  = (bid & 15) * 4 + wv;
    const int lane = threadIdx.x & 63;
    const int i  = lane;
    const float scale = 1.f / (HH * WW);

    float kw[NK][9];
    #pragma unroll
    for (int k = 0; k < NK; ++k) {
        const float* kp = kernels + ((size_t)(k * CO + o) * CI + i) * 9;
        #pragma unroll
        for (int t = 0; t < 9; ++t) kw[k][t] = kp[t];
    }

    const int a_ = lane & 15;
    float att;
    {
        float s = 0.f;
        const float* pv = pooled + b * CI;
        const float* wv_ = prep_w + a_ * CI;
        #pragma unroll
        for (int c = 0; c < CI; ++c) s += pv[c] * wv_[c];
        s = (s * scale - bn_m[a_]) * rsqrtf(bn_v[a_] + EPSBN) * bn_g[a_] + bn_b[a_];
        att = fmaxf(s, 0.f);
    }
    float av[CA];
    #pragma unroll
    for (int k = 0; k < CA; ++k) av[k] = __shfl(att, (lane & 48) + k);

    float cha_i, fa_o;
    {
        float s1 = fc_ch_b[i], s2 = fc_f_b[o];
        #pragma unroll
        for (int k = 0; k < CA; ++k) {
            s1 += av[k] * fc_ch_w[i * CA + k];
            s2 += av[k] * fc_f_w[o * CA + k];
        }
        cha_i = 1.f / (1.f + expf(-s1));
        fa_o  = 1.f / (1.f + expf(-s2));
    }
    float kav[NK];
    {
        float kv[NK], m = -1e30f;
        #pragma unroll
        for (int k = 0; k < NK; ++k) {
            float s = fc_k_b[k];
            #pragma unroll
            for (int t = 0; t < CA; ++t) s += av[t] * fc_k_w[k * CA + t];
            kv[k] = s; m = fmaxf(m, s);
        }
        float den = 0.f;
        #pragma unroll
        for (int k = 0; k < NK; ++k) { kv[k] = expf(kv[k] - m); den += kv[k]; }
        #pragma unroll
        for (int k = 0; k < NK; ++k) kav[k] = kv[k] / den;
    }
    float spv[9];
    #pragma unroll
    for (int t = 0; t < 9; ++t) {
        float s = fc_sp_b[t];
        #pragma unroll
        for (int k = 0; k < CA; ++k) s += av[k] * fc_sp_w[t * CA + k];
        spv[t] = 1.f / (1.f + expf(-s));
    }

    const float base = cha_i * fa_o;
    #pragma unroll
    for (int tap = 0; tap < 9; ++tap) {
        float s = 0.f;
        #pragma unroll
        for (int k = 0; k < NK; ++k) s += kav[k] * kw[k][tap];
        w2t[((size_t)(b * 9 + tap) * CO + o) * CI + i] = f2bf(s * spv[tap] * base);
    }
}

// ===========================================================================
// 3) FUSED conv (mfma_f32_16x16x32_bf16) — r16's proven structure verbatim:
//    dense-lane batched x staging (zeros-page select), A dbuf 2 x 12288
//    phase-pipelined via gload_lds, drain barriers, setprio around MFMA.
//    Block = 64co x 32col x 4row, 256 thr / 4 waves (cohalf x colh).
//    LDS 51200B = x 26624 (oct-XOR) + A dbuf 2 x 12288. 3 blocks/CU.
// ===========================================================================
#define ABASE 26624
#define ABUFB 12288

__global__ __launch_bounds__(256, 3) void conv_fused(const float* __restrict__ x,
                                                     const unsigned short* __restrict__ w2t,
                                                     const float* __restrict__ zeros,
                                                     float* __restrict__ out) {
    __shared__ __align__(16) unsigned char xs[ABASE + 2 * ABUFB];   // 51200
    const int tid  = threadIdx.x;
    const int lane = tid & 63;
    const int wv   = tid >> 6;
    const int orig = blockIdx.x;
    const int bid  = (orig & 7) * 512 + (orig >> 3);    // XCD swizzle (4096 = 8*512)
    const int b    = bid >> 7;
    const int rem  = bid & 127;
    const int colg = rem & 3;
    const int hg   = rem >> 2;
    const int h0 = hg * 4;
    const int w0 = colg * 32;

    const unsigned short* w2base = w2t + (size_t)b * 36864;

    // A chunk stager: chunk c = (ks = c/3, v = c%3) -> buf (c&1).
    auto stageA = [&](int c) {
        const int ks = c / 3, v = c - ks * 3;
        unsigned char* abuf = xs + ABASE + (c & 1) * ABUFB;
        for (int ch = wv; ch < 12; ch += 4) {
            const int u  = ch >> 2;
            const int q  = ch & 3;
            const unsigned short* g = w2base + (size_t)(u * 3 + v) * 4096
                                    + lane * 64 + ks * 32 + q * 8;
            gload_lds16(g, abuf + (ch << 10));
        }
    };

    // ---- x-stage, dense-lane mapping, BATCHED loads (zeros-page select)
    const int qlane = lane & 3;
    const int g     = lane >> 2;
    float4 La[9], Lb[9];
    #pragma unroll
    for (int it = 0; it < 9; ++it) {
        const int base = (wv * 9 + it) * 16;
        const int blk  = base >> 5;              // row*3 + iq
        const int row  = blk / 3;
        const int iq   = blk - row * 3;
        const int cip  = (base & 31) + g;        // 16 consecutive ci-pairs
        const int hh   = h0 - 1 + row;
        const int cg   = w0 - 8 + iq * 16 + qlane * 4;
        const bool ok  = ((unsigned)hh < (unsigned)HH) && ((unsigned)cg <= 124u);
        const float* p0 = x + ((size_t)(b * CI + 2 * cip) * HH + hh) * WW + cg;
        const float* pa = ok ? p0 : zeros;
        const float* pb = ok ? (p0 + HH * WW) : zeros;
        La[it] = *(const float4*)pa;
        Lb[it] = *(const float4*)pb;
    }
    // A chunk 0 in flight while we convert/write x
    stageA(0);

    #pragma unroll
    for (int it = 0; it < 9; ++it) {
        const int base = (wv * 9 + it) * 16;
        const int blk  = base >> 5;
        const int row  = blk / 3;
        const int iq   = blk - row * 3;
        const int cip  = (base & 31) + g;
        unsigned char* rbase = xs + row * 4352;
        const int oct = cip >> 2, lo = (cip & 3) * 4;
        const float av[4] = {La[it].x, La[it].y, La[it].z, La[it].w};
        const float cv[4] = {Lb[it].x, Lb[it].y, Lb[it].z, Lb[it].w};
        #pragma unroll
        for (int e = 0; e < 4; ++e) {
            const int cl_ = iq * 16 + qlane * 4 + e - 7;
            if ((unsigned)cl_ < 34u) {
                *(unsigned*)(rbase + cl_ * 128 + ((oct ^ (cl_ & 7)) << 4) + lo) =
                    cvt_pk_bf16(av[e], cv[e]);
            }
        }
    }
    __syncthreads();

    const int cl = lane & 15;        // pixel col in 16 / o in 16
    const int kq = lane >> 4;        // k-quarter within ks-half (8 ci)
    const int cohalf = wv & 1;
    const int colh   = wv >> 1;      // 0..1

    f32x4 acc[2][4];
    #pragma unroll
    for (int og = 0; og < 2; ++og)
        #pragma unroll
        for (int t = 0; t < 4; ++t)
            #pragma unroll
            for (int e = 0; e < 4; ++e) acc[og][t][e] = 0.f;

    const int lcol0 = colh * 16 + cl;
    const int aoff  = kq * 1024 + (cohalf * 32 + cl) * 16;

    // ---- 6 phases: stage chunk c+1 -> compute chunk c -> barrier
    #pragma unroll
    for (int c = 0; c < 6; ++c) {
        const int ks = c / 3, v = c - ks * 3;
        if (c < 5) stageA(c + 1);
        const unsigned char* abuf = xs + ABASE + (c & 1) * ABUFB;
        const int lcol = lcol0 + v;
        const int sw = ((ks << 2) + kq) ^ (lcol & 7);
        const unsigned char* bp = xs + (((lcol << 3) + sw) << 4);
        bf16x8 Bf[6];
        #pragma unroll
        for (int r = 0; r < 6; ++r) Bf[r] = *(const bf16x8*)(bp + r * 4352);
        __builtin_amdgcn_s_setprio(1);
        #pragma unroll
        for (int u = 0; u < 3; ++u) {
            const unsigned char* ap = abuf + u * 4096 + aoff;
            const bf16x8 A0 = *(const bf16x8*)(ap);
            const bf16x8 A1 = *(const bf16x8*)(ap + 256);     // og=1: +16 o
            #pragma unroll
            for (int t = 0; t < 4; ++t)
                acc[0][t] = __builtin_amdgcn_mfma_f32_16x16x32_bf16(A0, Bf[t + u], acc[0][t], 0, 0, 0);
            #pragma unroll
            for (int t = 0; t < 4; ++t)
                acc[1][t] = __builtin_amdgcn_mfma_f32_16x16x32_bf16(A1, Bf[t + u], acc[1][t], 0, 0, 0);
        }
        __builtin_amdgcn_s_setprio(0);
        if (c < 5) __syncthreads();
    }

    // ---- epilogue: o = cohalf*32 + og*16 + kq*4 + rg, col = w0 + colh*16 + cl
    #pragma unroll
    for (int og = 0; og < 2; ++og)
        #pragma unroll
        for (int t = 0; t < 4; ++t) {
            float* op = out + ((size_t)(b * CO + cohalf * 32 + og * 16 + kq * 4) * HH + h0 + t) * WW
                      + w0 + colh * 16 + cl;
            #pragma unroll
            for (int rg = 0; rg < 4; ++rg)
                op[(size_t)rg * (HH * WW)] = acc[og][t][rg];
        }
}

// ===========================================================================
extern "C" void kernel_launch(void* const* d_in, const int* in_sizes, int n_in,
                              void* d_out, int out_size, void* d_ws, size_t ws_size,
                              hipStream_t stream) {
    const float* x        = (const float*)d_in[0];
    const float* prep_w   = (const float*)d_in[1];
    const float* bn_g     = (const float*)d_in[2];
    const float* bn_b     = (const float*)d_in[3];
    const float* bn_m     = (const float*)d_in[4];
    const float* bn_v     = (const float*)d_in[5];
    const float* fc_sp_w  = (const float*)d_in[6];
    const float* fc_sp_b  = (const float*)d_in[7];
    const float* fc_ch_w  = (const float*)d_in[8];
    const float* fc_ch_b  = (const float*)d_in[9];
    const float* fc_f_w   = (const float*)d_in[10];
    const float* fc_f_b   = (const float*)d_in[11];
    const float* fc_k_w   = (const float*)d_in[12];
    const float* fc_k_b   = (const float*)d_in[13];
    const float* kernels  = (const float*)d_in[14];
    float* out = (float*)d_out;
    float* ws  = (float*)d_ws;

    float* zeros  = ws + WS_ZERO;
    float* pooled = ws + WS_POOLED;
    unsigned short* w2t = (unsigned short*)(ws + WS_W2T);

    pool_kernel<<<NB * CI, 256, 0, stream>>>(x, pooled, zeros);
    w2t3<<<NB * 16, 256, 0, stream>>>(kernels, pooled, prep_w,
                                      bn_g, bn_b, bn_m, bn_v,
                                      fc_sp_w, fc_sp_b, fc_ch_w, fc_ch_b,
                                      fc_f_w, fc_f_b, fc_k_w, fc_k_b, w2t);
    conv_fused<<<4096, 256, 0, stream>>>(x, w2t, zeros, out);
}